// Round 1
// baseline (661.381 us; speedup 1.0000x reference)
//
#include <hip/hip_runtime.h>

#define NROWS 50000
#define CDIM 8
#define XDIM 256
#define HDIM 256

typedef __attribute__((ext_vector_type(8))) short bf16x8;  // MFMA bf16 operand (4 VGPRs)
typedef __attribute__((ext_vector_type(4))) float f32x4;   // MFMA accumulator

// fp32 -> bf16 round-to-nearest-even
__device__ __forceinline__ unsigned short f2bf_rne(float f) {
    unsigned int u = __builtin_bit_cast(unsigned int, f);
    u += 0x7fffu + ((u >> 16) & 1u);
    return (unsigned short)(u >> 16);
}

__device__ __forceinline__ bf16x8 pack8(const f32x4 a, const f32x4 b) {
    bf16x8 r;
    r[0] = (short)f2bf_rne(a[0]);
    r[1] = (short)f2bf_rne(a[1]);
    r[2] = (short)f2bf_rne(a[2]);
    r[3] = (short)f2bf_rne(a[3]);
    r[4] = (short)f2bf_rne(b[0]);
    r[5] = (short)f2bf_rne(b[1]);
    r[6] = (short)f2bf_rne(b[2]);
    r[7] = (short)f2bf_rne(b[3]);
    return r;
}

// Fully fused, NO workspace use. Weight fragments for each xc-slice (48 KiB:
// 3 segs x 16 h-tiles x 64 lanes x 16 B) are built per-block in LDS from the
// fp32 weights (L2-resident, 786 KB), then consumed by MFMA exactly as the
// previous wp-packed layout:
//   frag value[lane][j] = W_seg[ xc*32 + (lane>>4)*8 + j ][ ht*16 + (lane&15) ]
// One wave computes out[16 rows][256 h]; block = 4 waves = 64 rows.
// D layout (16x16, verified m89): col = lane&15 = row_local, row = quad*4+reg = h_local.
__global__ __launch_bounds__(256) void tbcnn_fused(
        const float* __restrict__ child, const float* __restrict__ parent,
        const float* __restrict__ Wl, const float* __restrict__ Wr,
        const float* __restrict__ Wt, const float* __restrict__ bias,
        float* __restrict__ out) {
    __shared__ bf16x8 wlds[3 * 16 * 64];   // 48 KiB: [seg][ht][lane]

    const int tid  = threadIdx.x;
    const int wave = tid >> 6;
    const int lane = tid & 63;
    const int row0 = (blockIdx.x * 4 + wave) * 16;
    const bool active = (row0 < NROWS);     // inactive waves still stage + sync

    const int rmod = lane & 15;             // row_local (B-operand n / D col)
    const int quad = lane >> 4;             // k-octet selector
    const int row  = active ? (row0 + rmod) : 0;

    const float* __restrict__ chrow = child  + (size_t)row * (CDIM * XDIM);
    const float* __restrict__ prow  = parent + (size_t)row * XDIM;

    // positional tree weights, fp32 exact same constants as reference
    const float lwt[8] = {7.f/7.f, 6.f/7.f, 5.f/7.f, 4.f/7.f, 3.f/7.f, 2.f/7.f, 1.f/7.f, 0.f/7.f};
    const float rwt[8] = {0.f/7.f, 1.f/7.f, 2.f/7.f, 3.f/7.f, 4.f/7.f, 5.f/7.f, 6.f/7.f, 7.f/7.f};

    f32x4 acc[16];
#pragma unroll
    for (int t = 0; t < 16; ++t) acc[t] = (f32x4){0.f, 0.f, 0.f, 0.f};

    // staging decomposition (constant per thread): fragment-lane = tid&63,
    // tiles k*4 + wave for k = 0..11  (covers tiles 0..47)
    const int fx = (lane >> 4) * 8;         // x offset within the 32-x slice
    const int fh = lane & 15;               // h offset within the 16-h tile

#pragma unroll 1
    for (int xc = 0; xc < 8; ++xc) {
        const int x0 = xc * 32 + quad * 8;   // this lane's 8 x's (compute phase)

        // ---- B-operand fragments from registers (independent of LDS) ----
        bf16x8 fL, fR, fP;
        if (active) {
            f32x4 sl0 = (f32x4){0.f,0.f,0.f,0.f}, sl1 = (f32x4){0.f,0.f,0.f,0.f};
            f32x4 sr0 = (f32x4){0.f,0.f,0.f,0.f}, sr1 = (f32x4){0.f,0.f,0.f,0.f};
#pragma unroll
            for (int c = 0; c < CDIM; ++c) {
                const f32x4* p = (const f32x4*)(chrow + (size_t)c * XDIM + x0);
                f32x4 a = p[0];
                f32x4 b = p[1];
                sl0 += a * lwt[c];  sl1 += b * lwt[c];
                sr0 += a * rwt[c];  sr1 += b * rwt[c];
            }
            const f32x4* pp = (const f32x4*)(prow + x0);
            f32x4 p0 = pp[0];
            f32x4 p1 = pp[1];
            fL = pack8(sl0, sl1);
            fR = pack8(sr0, sr1);
            fP = pack8(p0, p1);
        }

        // ---- stage this xc's weight fragments into LDS (all 256 threads) ----
        // wave w stages tiles {w, w+4, ..., w+44}; per tile: 8 strided fp32
        // loads (L2-hot) -> bf16x8 -> one contiguous ds_write_b128 (no conflicts)
#pragma unroll 2
        for (int k = 0; k < 12; ++k) {
            const int tile = k * 4 + wave;       // 0..47 = seg*16 + ht
            const int ht  = tile & 15;
            const int seg = tile >> 4;
            const float* __restrict__ W = (seg == 0) ? Wl : (seg == 1) ? Wr : Wt;
            const float* __restrict__ wp = W + (size_t)(xc * 32 + fx) * HDIM + (ht * 16 + fh);
            bf16x8 fr;
#pragma unroll
            for (int j = 0; j < 8; ++j)
                fr[j] = (short)f2bf_rne(wp[(size_t)j * HDIM]);
            wlds[tile * 64 + lane] = fr;
        }
        __syncthreads();

        // ---- 3 k-steps (left / right / top), 16 h-tiles each ----
        if (active) {
            const bf16x8* wLp = &wlds[(0 * 16) * 64 + lane];
            const bf16x8* wRp = &wlds[(1 * 16) * 64 + lane];
            const bf16x8* wTp = &wlds[(2 * 16) * 64 + lane];
#pragma unroll
            for (int ht = 0; ht < 16; ++ht)
                acc[ht] = __builtin_amdgcn_mfma_f32_16x16x32_bf16(wLp[ht * 64], fL, acc[ht], 0, 0, 0);
#pragma unroll
            for (int ht = 0; ht < 16; ++ht)
                acc[ht] = __builtin_amdgcn_mfma_f32_16x16x32_bf16(wRp[ht * 64], fR, acc[ht], 0, 0, 0);
#pragma unroll
            for (int ht = 0; ht < 16; ++ht)
                acc[ht] = __builtin_amdgcn_mfma_f32_16x16x32_bf16(wTp[ht * 64], fP, acc[ht], 0, 0, 0);
        }
        __syncthreads();   // LDS reused next xc
    }

    // ---- epilogue: bias + relu, float4 stores (4 consecutive h per tile) ----
    if (active) {
        float* __restrict__ orow = out + (size_t)row * HDIM;  // D col = lane&15 = row_local
#pragma unroll
        for (int ht = 0; ht < 16; ++ht) {
            const int h = ht * 16 + quad * 4;
            f32x4 b4 = *(const f32x4*)(bias + h);
            f32x4 v = acc[ht];
            v[0] = fmaxf(v[0] + b4[0], 0.f);
            v[1] = fmaxf(v[1] + b4[1], 0.f);
            v[2] = fmaxf(v[2] + b4[2], 0.f);
            v[3] = fmaxf(v[3] + b4[3], 0.f);
            *(f32x4*)(orow + h) = v;
        }
    }
}

extern "C" void kernel_launch(void* const* d_in, const int* in_sizes, int n_in,
                              void* d_out, int out_size, void* d_ws, size_t ws_size,
                              hipStream_t stream) {
    const float* child  = (const float*)d_in[0];
    const float* parent = (const float*)d_in[1];
    const float* Wl     = (const float*)d_in[2];
    const float* Wr     = (const float*)d_in[3];
    const float* Wt     = (const float*)d_in[4];
    const float* bias   = (const float*)d_in[5];
    float* out = (float*)d_out;

    // NO workspace use: weights are fragment-packed per-block in LDS.
    const int n_wtasks = NROWS / 16;                 // 3125
    const int n_blocks = (n_wtasks + 3) / 4;         // 782
    tbcnn_fused<<<n_blocks, 256, 0, stream>>>(child, parent, Wl, Wr, Wt, bias, out);
    (void)d_ws; (void)ws_size;
}